// Round 1
// baseline (620.487 us; speedup 1.0000x reference)
//
#include <hip/hip_runtime.h>
#include <stdint.h>

typedef __attribute__((ext_vector_type(8))) short s16x8;
typedef __attribute__((ext_vector_type(4))) float f32x4;

__device__ __forceinline__ unsigned short f2bf(float f) {
  unsigned int u = __float_as_uint(f);
  u += 0x7fffu + ((u >> 16) & 1u);
  return (unsigned short)(u >> 16);
}
__device__ __forceinline__ float bf2f(unsigned short h) {
  return __uint_as_float(((unsigned int)h) << 16);
}
__device__ __forceinline__ f32x4 mfma16(s16x8 a, s16x8 b, f32x4 c) {
  return __builtin_amdgcn_mfma_f32_16x16x32_bf16(a, b, c, 0, 0, 0);
}

// ---------------- attention kernel: one block per batch ----------------
// LDS plan (union):
//  phase 1/2 (S = Q K^T):  Kh[64][136] @0 (17408 B), Kl[64][136] @17408  -> 34816 B
//  phase 3  (A = P V):     Vt[256][72] @0 (36864 B), P[64][72] @36864    -> 46080 B
// Pipelining: K for BOTH e-phases is loaded to regs at entry; V is loaded to
// regs during the S phases. Barrier structure unchanged (plain __syncthreads).
#define KH_STR 136
#define VT_STR 72
#define P_STR  72

__global__ __launch_bounds__(256, 3) void attn_kernel(
    const float* __restrict__ Vg, const float* __restrict__ Kg,
    const float* __restrict__ Qg, float* __restrict__ attn_out,
    unsigned short* __restrict__ xb /* bf16 x = attn+q, may be null */) {
  __shared__ __align__(16) char smem[46080];
  unsigned short* KhL = (unsigned short*)smem;
  unsigned short* KlL = (unsigned short*)(smem + 17408);
  unsigned short* VtL = (unsigned short*)smem;
  unsigned short* PL  = (unsigned short*)(smem + 36864);

  const int b = blockIdx.x;
  const int tid = threadIdx.x;
  const int lane = tid & 63;
  const int w = tid >> 6;       // wave id: owns S/A rows 16w..16w+15
  const int n = lane & 15;
  const int q = lane >> 4;

  const float* Qb = Qg + (size_t)b * 64 * 256;
  const float* Kb = Kg + (size_t)b * 64 * 256;
  const float* Vb = Vg + (size_t)b * 64 * 256;

  const int kr0 = tid >> 5;   // K staging row base (row = it*8 + kr0)
  const int kc4 = tid & 31;   // K staging float4 column

  f32x4 accS[4];
#pragma unroll
  for (int c = 0; c < 4; ++c) accS[c] = f32x4{0.f, 0.f, 0.f, 0.f};

  // ---- issue K loads for BOTH 128-wide e-chunks up front ----
  float4 k1[8], k2[8];
#pragma unroll
  for (int it = 0; it < 8; ++it)
    k1[it] = *(const float4*)(Kb + (it * 8 + kr0) * 256 + kc4 * 4);
#pragma unroll
  for (int it = 0; it < 8; ++it)
    k2[it] = *(const float4*)(Kb + (it * 8 + kr0) * 256 + 128 + kc4 * 4);

  // ---- stage phase-1 K (hi/lo bf16) ----
#pragma unroll
  for (int it = 0; it < 8; ++it) {
    float4 v = k1[it];
    ushort4 hi, lo;
    hi.x = f2bf(v.x); lo.x = f2bf(v.x - bf2f(hi.x));
    hi.y = f2bf(v.y); lo.y = f2bf(v.y - bf2f(hi.y));
    hi.z = f2bf(v.z); lo.z = f2bf(v.z - bf2f(hi.z));
    hi.w = f2bf(v.w); lo.w = f2bf(v.w - bf2f(hi.w));
    int row = it * 8 + kr0;
    *(ushort4*)(KhL + row * KH_STR + kc4 * 4) = hi;
    *(ushort4*)(KlL + row * KH_STR + kc4 * 4) = lo;
  }
  __syncthreads();

  // ---- S accumulation over one 128-wide e-chunk ----
  auto s_phase = [&](int e0) {
#pragma unroll
    for (int kk = 0; kk < 4; ++kk) {
      const float* qsrc = Qb + (16 * w + n) * 256 + e0 + kk * 32 + q * 8;
      float4 a0 = *(const float4*)qsrc;
      float4 a1 = *(const float4*)(qsrc + 4);
      float av[8] = {a0.x, a0.y, a0.z, a0.w, a1.x, a1.y, a1.z, a1.w};
      s16x8 qh, ql;
#pragma unroll
      for (int j = 0; j < 8; ++j) {
        unsigned short h = f2bf(av[j]);
        qh[j] = (short)h;
        ql[j] = (short)f2bf(av[j] - bf2f(h));
      }
      const int colb = kk * 32 + q * 8;
#pragma unroll
      for (int c = 0; c < 4; ++c) {
        s16x8 kh = *(const s16x8*)(KhL + (16 * c + n) * KH_STR + colb);
        s16x8 kl = *(const s16x8*)(KlL + (16 * c + n) * KH_STR + colb);
        accS[c] = mfma16(qh, kh, accS[c]);
        accS[c] = mfma16(qh, kl, accS[c]);
        accS[c] = mfma16(ql, kh, accS[c]);
      }
    }
  };

  // issue first half of V (t=0..31) so it flies under phase-1 compute
  float v0r[32];
#pragma unroll
  for (int t = 0; t < 32; ++t) v0r[t] = Vb[t * 256 + tid];

  s_phase(0);
  __syncthreads();

  // ---- stage phase-2 K (pure reg->LDS, no global wait) ----
#pragma unroll
  for (int it = 0; it < 8; ++it) {
    float4 v = k2[it];
    ushort4 hi, lo;
    hi.x = f2bf(v.x); lo.x = f2bf(v.x - bf2f(hi.x));
    hi.y = f2bf(v.y); lo.y = f2bf(v.y - bf2f(hi.y));
    hi.z = f2bf(v.z); lo.z = f2bf(v.z - bf2f(hi.z));
    hi.w = f2bf(v.w); lo.w = f2bf(v.w - bf2f(hi.w));
    int row = it * 8 + kr0;
    *(ushort4*)(KhL + row * KH_STR + kc4 * 4) = hi;
    *(ushort4*)(KlL + row * KH_STR + kc4 * 4) = lo;
  }
  // issue second half of V; partially covered by phase-2 compute
  float v1r[32];
#pragma unroll
  for (int t = 0; t < 32; ++t) v1r[t] = Vb[(32 + t) * 256 + tid];
  __syncthreads();

  s_phase(128);

  // ---- in-register softmax. lane holds S[16w+4q+r][16c+n] in accS[c][r] ----
  const float scale = 0.125f;
  float p[4][4];
#pragma unroll
  for (int r = 0; r < 4; ++r) {
    float m = -1e30f;
#pragma unroll
    for (int c = 0; c < 4; ++c) m = fmaxf(m, accS[c][r]);
#pragma unroll
    for (int mk = 1; mk < 16; mk <<= 1) m = fmaxf(m, __shfl_xor(m, mk, 64));
    float s = 0.f;
#pragma unroll
    for (int c = 0; c < 4; ++c) {
      float e = __expf((accS[c][r] - m) * scale);
      p[c][r] = e;
      s += e;
    }
#pragma unroll
    for (int mk = 1; mk < 16; mk <<= 1) s += __shfl_xor(s, mk, 64);
    float inv = 1.0f / s;
#pragma unroll
    for (int c = 0; c < 4; ++c) p[c][r] *= inv;
  }

  // ---- store P (region disjoint from K staging, safe pre-barrier) ----
#pragma unroll
  for (int r = 0; r < 4; ++r) {
    int row = 16 * w + 4 * q + r;
#pragma unroll
    for (int c = 0; c < 4; ++c) PL[row * P_STR + 16 * c + n] = f2bf(p[c][r]);
  }
  __syncthreads();  // all phase-2 K reads done -> Vt region free

  // ---- store V^T (bf16, from prefetched regs) ----
#pragma unroll
  for (int t2 = 0; t2 < 16; ++t2) {
    unsigned int pk = (unsigned int)f2bf(v0r[2 * t2]) |
                      ((unsigned int)f2bf(v0r[2 * t2 + 1]) << 16);
    *(unsigned int*)(VtL + tid * VT_STR + 2 * t2) = pk;
  }
#pragma unroll
  for (int t2 = 0; t2 < 16; ++t2) {
    unsigned int pk = (unsigned int)f2bf(v1r[2 * t2]) |
                      ((unsigned int)f2bf(v1r[2 * t2 + 1]) << 16);
    *(unsigned int*)(VtL + tid * VT_STR + 32 + 2 * t2) = pk;
  }
  __syncthreads();

  // ---- A = P V via MFMA, wave w does rows 16w..16w+15, all 256 cols ----
  f32x4 accA[16];
#pragma unroll
  for (int c = 0; c < 16; ++c) accA[c] = f32x4{0.f, 0.f, 0.f, 0.f};
#pragma unroll
  for (int ks = 0; ks < 2; ++ks) {
    const int colb = ks * 32 + q * 8;
    s16x8 af = *(const s16x8*)(PL + (16 * w + n) * P_STR + colb);
#pragma unroll
    for (int c = 0; c < 16; ++c) {
      s16x8 bf = *(const s16x8*)(VtL + (16 * c + n) * VT_STR + colb);
      accA[c] = mfma16(af, bf, accA[c]);
    }
  }

  // ---- epilogue: attention (fp32) and x = attention + query (bf16) ----
#pragma unroll
  for (int r = 0; r < 4; ++r) {
    int t = 16 * w + 4 * q + r;
    size_t base = ((size_t)b * 64 + t) * 256;
#pragma unroll
    for (int c = 0; c < 16; ++c) {
      int e = 16 * c + n;
      float aval = accA[c][r];
      attn_out[base + e] = aval;
      if (xb) xb[base + e] = f2bf(aval + Qb[t * 256 + e]);
    }
  }
}

// ---------------- W_ff fp32 -> bf16 ----------------
__global__ __launch_bounds__(256) void w2b_kernel(const float* __restrict__ W,
                                                  unsigned short* __restrict__ Wb) {
  int i = blockIdx.x * 256 + threadIdx.x;  // one float4 each, grid covers exactly
  float4 v = ((const float4*)W)[i];
  ushort4 o;
  o.x = f2bf(v.x); o.y = f2bf(v.y); o.z = f2bf(v.z); o.w = f2bf(v.w);
  ((ushort4*)Wb)[i] = o;
}

// ---------------- FF GEMM: out_part = x @ W^T, 64x64 tiles, K-split ----------------
// 1D grid, XCD-bijective swizzle: each XCD's L2 holds one z-slab of W.
// Register double-buffer: next K-step's loads issued during current compute.
template <bool USE_XB>
__global__ __launch_bounds__(256, 4) void ff_kernel(
    const unsigned short* __restrict__ xb, const float* __restrict__ attn,
    const float* __restrict__ query, const unsigned short* __restrict__ Wb,
    float* __restrict__ part, int kchunk) {
  __shared__ __align__(16) unsigned short As[64 * 72];
  __shared__ __align__(16) unsigned short Bs[64 * 72];
  const int tid = threadIdx.x;
  const int lane = tid & 63, w = tid >> 6, n = lane & 15, q = lane >> 4;

  const int chunk = (int)gridDim.x >> 3;  // gridDim.x is a multiple of 8
  const int s = ((int)blockIdx.x & 7) * chunk + ((int)blockIdx.x >> 3);
  const int m0 = (s & 31) * 64;
  const int rest = s >> 5;
  const int n0 = (rest & 3) * 64;
  const int z = rest >> 2;
  const int k0 = z * kchunk;

  f32x4 acc[4];
#pragma unroll
  for (int c = 0; c < 4; ++c) acc[c] = f32x4{0.f, 0.f, 0.f, 0.f};

  const int srow = tid >> 3;       // 0..31
  const int scol = (tid & 7) * 8;

  uint4 pa[2], pb[2];
  float4 fa[2][4];

  auto gload = [&](int kk) {
#pragma unroll
    for (int rr = 0; rr < 2; ++rr) {
      int row = rr * 32 + srow;
      size_t gw = (size_t)(n0 + row) * 16384 + k0 + kk + scol;
      pb[rr] = *(const uint4*)(Wb + gw);
      size_t ga = (size_t)(m0 + row) * 16384 + k0 + kk + scol;
      if constexpr (USE_XB) {
        pa[rr] = *(const uint4*)(xb + ga);
      } else {
        fa[rr][0] = *(const float4*)(attn + ga);
        fa[rr][1] = *(const float4*)(attn + ga + 4);
        fa[rr][2] = *(const float4*)(query + ga);
        fa[rr][3] = *(const float4*)(query + ga + 4);
      }
    }
  };

  gload(0);
  for (int kk = 0; kk < kchunk; kk += 64) {
#pragma unroll
    for (int rr = 0; rr < 2; ++rr) {
      int row = rr * 32 + srow;
      if constexpr (USE_XB) {
        *(uint4*)(As + row * 72 + scol) = pa[rr];
      } else {
        ushort4 h0, h1;
        h0.x = f2bf(fa[rr][0].x + fa[rr][2].x);
        h0.y = f2bf(fa[rr][0].y + fa[rr][2].y);
        h0.z = f2bf(fa[rr][0].z + fa[rr][2].z);
        h0.w = f2bf(fa[rr][0].w + fa[rr][2].w);
        h1.x = f2bf(fa[rr][1].x + fa[rr][3].x);
        h1.y = f2bf(fa[rr][1].y + fa[rr][3].y);
        h1.z = f2bf(fa[rr][1].z + fa[rr][3].z);
        h1.w = f2bf(fa[rr][1].w + fa[rr][3].w);
        *(ushort4*)(As + row * 72 + scol) = h0;
        *(ushort4*)(As + row * 72 + scol + 4) = h1;
      }
      *(uint4*)(Bs + row * 72 + scol) = pb[rr];
    }
    __syncthreads();
    if (kk + 64 < kchunk) gload(kk + 64);  // overlap with compute
#pragma unroll
    for (int ks = 0; ks < 2; ++ks) {
      const int colb = ks * 32 + q * 8;
      s16x8 af = *(const s16x8*)(As + (16 * w + n) * 72 + colb);
#pragma unroll
      for (int c = 0; c < 4; ++c) {
        s16x8 bf = *(const s16x8*)(Bs + (16 * c + n) * 72 + colb);
        acc[c] = mfma16(af, bf, acc[c]);
      }
    }
    __syncthreads();
  }
#pragma unroll
  for (int r = 0; r < 4; ++r) {
    int m = m0 + 16 * w + 4 * q + r;
#pragma unroll
    for (int c = 0; c < 4; ++c) {
      int nn = n0 + 16 * c + n;
      part[((size_t)z * 2048 + m) * 256 + nn] = acc[c][r];
    }
  }
}

// ---------------- reduce K-split partials + bias + ReLU (float4) ----------------
__global__ __launch_bounds__(256) void relu_kernel(const float* __restrict__ part,
                                                   const float* __restrict__ bias,
                                                   float* __restrict__ out, int KS) {
  int i4 = blockIdx.x * 256 + threadIdx.x;  // float4 index, 131072 total
  const float4* p4 = (const float4*)part;
  float4 s = ((const float4*)bias)[i4 & 63];
  for (int ks = 0; ks < KS; ++ks) {
    float4 v = p4[(size_t)ks * 131072 + i4];
    s.x += v.x; s.y += v.y; s.z += v.z; s.w += v.w;
  }
  float4 o;
  o.x = fmaxf(s.x, 0.f); o.y = fmaxf(s.y, 0.f);
  o.z = fmaxf(s.z, 0.f); o.w = fmaxf(s.w, 0.f);
  ((float4*)out)[i4] = o;
}

extern "C" void kernel_launch(void* const* d_in, const int* in_sizes, int n_in,
                              void* d_out, int out_size, void* d_ws, size_t ws_size,
                              hipStream_t stream) {
  const float* value = (const float*)d_in[0];
  const float* key   = (const float*)d_in[1];
  const float* query = (const float*)d_in[2];
  // d_in[3] = mask, unused by the block
  const float* W_ff  = (const float*)d_in[4];
  const float* b_ff  = (const float*)d_in[5];

  float* out  = (float*)d_out;
  float* attn = out + (size_t)2048 * 256;  // outputs: (out, attention) concatenated

  const size_t wb_bytes = (size_t)256 * 16384 * 2;      // 8 MB bf16 W
  const size_t xb_bytes = (size_t)2048 * 64 * 256 * 2;  // 64 MB bf16 x
  const size_t slab     = (size_t)2048 * 256 * 4;       // 2 MB per K-split slab

  int KS;
  bool use_xb;
  if (ws_size >= wb_bytes + 8 * slab + xb_bytes) {
    KS = 8; use_xb = true;                 // preferred: 4 blocks/CU in ff
  } else if (ws_size >= wb_bytes + 4 * slab + xb_bytes) {
    KS = 4; use_xb = true;                 // previous session's footprint
  } else {
    KS = 8; use_xb = false;                // ff recomputes x from attn+query
  }
  const size_t part_bytes = (size_t)KS * slab;

  unsigned short* Wb = (unsigned short*)d_ws;
  float* part = (float*)((char*)d_ws + wb_bytes);
  unsigned short* xb =
      use_xb ? (unsigned short*)((char*)d_ws + wb_bytes + part_bytes) : nullptr;

  w2b_kernel<<<4096, 256, 0, stream>>>(W_ff, Wb);
  attn_kernel<<<2048, 256, 0, stream>>>(value, key, query, attn, xb);
  if (use_xb)
    ff_kernel<true><<<32 * 4 * KS, 256, 0, stream>>>(xb, nullptr, nullptr, Wb, part,
                                                     16384 / KS);
  else
    ff_kernel<false><<<32 * 4 * KS, 256, 0, stream>>>(nullptr, attn, query, Wb, part,
                                                      16384 / KS);
  relu_kernel<<<512, 256, 0, stream>>>(part, b_ff, out, KS);
}

// Round 2
// 511.946 us; speedup vs baseline: 1.2120x; 1.2120x over previous
//
#include <hip/hip_runtime.h>
#include <stdint.h>

typedef __attribute__((ext_vector_type(8))) short s16x8;
typedef __attribute__((ext_vector_type(4))) float f32x4;

__device__ __forceinline__ unsigned short f2bf(float f) {
  unsigned int u = __float_as_uint(f);
  u += 0x7fffu + ((u >> 16) & 1u);
  return (unsigned short)(u >> 16);
}
__device__ __forceinline__ float bf2f(unsigned short h) {
  return __uint_as_float(((unsigned int)h) << 16);
}
__device__ __forceinline__ f32x4 mfma16(s16x8 a, s16x8 b, f32x4 c) {
  return __builtin_amdgcn_mfma_f32_16x16x32_bf16(a, b, c, 0, 0, 0);
}

// ---------------- attention kernel: one block per batch ----------------
// (byte-identical to the 574 us round-0 version; revert of the failed
//  register-prefetch experiment — compiler sank the loads, VGPR proved it)
// LDS plan (union):
//  phase 1/2 (S = Q K^T):  Kh[64][136] @0 (17408 B), Kl[64][136] @17408  -> 34816 B
//  phase 3  (A = P V):     Vt[256][72] @0 (36864 B), P[64][72] @36864    -> 46080 B
#define KH_STR 136
#define VT_STR 72
#define P_STR  72

__global__ __launch_bounds__(256) void attn_kernel(
    const float* __restrict__ Vg, const float* __restrict__ Kg,
    const float* __restrict__ Qg, float* __restrict__ attn_out,
    unsigned short* __restrict__ xb /* bf16 x = attn+q, may be null */) {
  __shared__ __align__(16) char smem[46080];
  unsigned short* KhL = (unsigned short*)smem;
  unsigned short* KlL = (unsigned short*)(smem + 17408);
  unsigned short* VtL = (unsigned short*)smem;
  unsigned short* PL  = (unsigned short*)(smem + 36864);

  const int b = blockIdx.x;
  const int tid = threadIdx.x;
  const int lane = tid & 63;
  const int w = tid >> 6;       // wave id: owns S/A rows 16w..16w+15
  const int n = lane & 15;
  const int q = lane >> 4;

  const float* Qb = Qg + (size_t)b * 64 * 256;
  const float* Kb = Kg + (size_t)b * 64 * 256;
  const float* Vb = Vg + (size_t)b * 64 * 256;

  f32x4 accS[4];
#pragma unroll
  for (int c = 0; c < 4; ++c) accS[c] = f32x4{0.f, 0.f, 0.f, 0.f};

  // ---- S = Q K^T, hi/lo bf16 split, two 128-wide e-chunks ----
  for (int ph = 0; ph < 2; ++ph) {
    const int e0 = ph * 128;
    // stage K chunk 64x128 fp32 -> hi/lo bf16 LDS
#pragma unroll
    for (int it = 0; it < 8; ++it) {
      int i = it * 256 + tid;
      int row = i >> 5;
      int c4 = i & 31;
      float4 v = *(const float4*)(Kb + row * 256 + e0 + c4 * 4);
      ushort4 hi, lo;
      hi.x = f2bf(v.x); lo.x = f2bf(v.x - bf2f(hi.x));
      hi.y = f2bf(v.y); lo.y = f2bf(v.y - bf2f(hi.y));
      hi.z = f2bf(v.z); lo.z = f2bf(v.z - bf2f(hi.z));
      hi.w = f2bf(v.w); lo.w = f2bf(v.w - bf2f(hi.w));
      *(ushort4*)(KhL + row * KH_STR + c4 * 4) = hi;
      *(ushort4*)(KlL + row * KH_STR + c4 * 4) = lo;
    }
    __syncthreads();
#pragma unroll
    for (int kk = 0; kk < 4; ++kk) {
      const float* qsrc = Qb + (16 * w + n) * 256 + e0 + kk * 32 + q * 8;
      float4 a0 = *(const float4*)qsrc;
      float4 a1 = *(const float4*)(qsrc + 4);
      float av[8] = {a0.x, a0.y, a0.z, a0.w, a1.x, a1.y, a1.z, a1.w};
      s16x8 qh, ql;
#pragma unroll
      for (int j = 0; j < 8; ++j) {
        unsigned short h = f2bf(av[j]);
        qh[j] = (short)h;
        ql[j] = (short)f2bf(av[j] - bf2f(h));
      }
      const int colb = kk * 32 + q * 8;
#pragma unroll
      for (int c = 0; c < 4; ++c) {
        s16x8 kh = *(const s16x8*)(KhL + (16 * c + n) * KH_STR + colb);
        s16x8 kl = *(const s16x8*)(KlL + (16 * c + n) * KH_STR + colb);
        accS[c] = mfma16(qh, kh, accS[c]);
        accS[c] = mfma16(qh, kl, accS[c]);
        accS[c] = mfma16(ql, kh, accS[c]);
      }
    }
    __syncthreads();  // before restaging / Vt overwrite
  }

  // ---- in-register softmax. lane holds S[16w+4q+r][16c+n] in accS[c][r] ----
  const float scale = 0.125f;
  float p[4][4];
#pragma unroll
  for (int r = 0; r < 4; ++r) {
    float m = -1e30f;
#pragma unroll
    for (int c = 0; c < 4; ++c) m = fmaxf(m, accS[c][r]);
#pragma unroll
    for (int mk = 1; mk < 16; mk <<= 1) m = fmaxf(m, __shfl_xor(m, mk, 64));
    float s = 0.f;
#pragma unroll
    for (int c = 0; c < 4; ++c) {
      float e = __expf((accS[c][r] - m) * scale);
      p[c][r] = e;
      s += e;
    }
#pragma unroll
    for (int mk = 1; mk < 16; mk <<= 1) s += __shfl_xor(s, mk, 64);
    float inv = 1.0f / s;
#pragma unroll
    for (int c = 0; c < 4; ++c) p[c][r] *= inv;
  }

  // ---- stage V^T (bf16) and P (bf16, A-layout source) ----
#pragma unroll 4
  for (int t2 = 0; t2 < 32; ++t2) {
    int t = t2 * 2;
    float v0 = Vb[t * 256 + tid];
    float v1 = Vb[(t + 1) * 256 + tid];
    unsigned int pk = (unsigned int)f2bf(v0) | ((unsigned int)f2bf(v1) << 16);
    *(unsigned int*)(VtL + tid * VT_STR + t) = pk;
  }
#pragma unroll
  for (int r = 0; r < 4; ++r) {
    int row = 16 * w + 4 * q + r;
#pragma unroll
    for (int c = 0; c < 4; ++c) PL[row * P_STR + 16 * c + n] = f2bf(p[c][r]);
  }
  __syncthreads();

  // ---- A = P V via MFMA, wave w does rows 16w..16w+15, all 256 cols ----
  f32x4 accA[16];
#pragma unroll
  for (int c = 0; c < 16; ++c) accA[c] = f32x4{0.f, 0.f, 0.f, 0.f};
#pragma unroll
  for (int ks = 0; ks < 2; ++ks) {
    const int colb = ks * 32 + q * 8;
    s16x8 af = *(const s16x8*)(PL + (16 * w + n) * P_STR + colb);
#pragma unroll
    for (int c = 0; c < 16; ++c) {
      s16x8 bf = *(const s16x8*)(VtL + (16 * c + n) * VT_STR + colb);
      accA[c] = mfma16(af, bf, accA[c]);
    }
  }

  // ---- epilogue: attention (fp32) and x = attention + query (bf16) ----
#pragma unroll
  for (int r = 0; r < 4; ++r) {
    int t = 16 * w + 4 * q + r;
    size_t base = ((size_t)b * 64 + t) * 256;
#pragma unroll
    for (int c = 0; c < 16; ++c) {
      int e = 16 * c + n;
      float aval = accA[c][r];
      attn_out[base + e] = aval;
      if (xb) xb[base + e] = f2bf(aval + Qb[t * 256 + e]);
    }
  }
}

// ---------------- W_ff fp32 -> bf16 ----------------
__global__ __launch_bounds__(256) void w2b_kernel(const float* __restrict__ W,
                                                  unsigned short* __restrict__ Wb) {
  int i = blockIdx.x * 256 + threadIdx.x;  // one float4 each, grid covers exactly
  float4 v = ((const float4*)W)[i];
  ushort4 o;
  o.x = f2bf(v.x); o.y = f2bf(v.y); o.z = f2bf(v.z); o.w = f2bf(v.w);
  ((ushort4*)Wb)[i] = o;
}

// ---------------- FF GEMM: out_part = x @ W^T, 64x64 tiles, K-split ----------------
// (byte-identical body to round 0 — only the launch KS changes: 2048 blocks at
//  KS=16 gives 8 blocks/CU vs round-0's 2, hiding the serial K-loop latency)
template <bool USE_XB>
__global__ __launch_bounds__(256) void ff_kernel(
    const unsigned short* __restrict__ xb, const float* __restrict__ attn,
    const float* __restrict__ query, const unsigned short* __restrict__ Wb,
    float* __restrict__ part, int kchunk) {
  __shared__ __align__(16) unsigned short As[64 * 72];
  __shared__ __align__(16) unsigned short Bs[64 * 72];
  const int tid = threadIdx.x;
  const int lane = tid & 63, w = tid >> 6, n = lane & 15, q = lane >> 4;
  const int m0 = blockIdx.x * 64;
  const int n0 = blockIdx.y * 64;
  const int k0 = blockIdx.z * kchunk;

  f32x4 acc[4];
#pragma unroll
  for (int c = 0; c < 4; ++c) acc[c] = f32x4{0.f, 0.f, 0.f, 0.f};

  const int srow = tid >> 3;  // 0..31
  const int scol = (tid & 7) * 8;

  for (int kk = 0; kk < kchunk; kk += 64) {
#pragma unroll
    for (int rr = 0; rr < 2; ++rr) {
      int row = rr * 32 + srow;
      size_t ga = (size_t)(m0 + row) * 16384 + k0 + kk + scol;
      if (USE_XB) {
        *(uint4*)(As + row * 72 + scol) = *(const uint4*)(xb + ga);
      } else {
        float4 a0 = *(const float4*)(attn + ga);
        float4 a1 = *(const float4*)(attn + ga + 4);
        float4 q0 = *(const float4*)(query + ga);
        float4 q1 = *(const float4*)(query + ga + 4);
        ushort4 h0, h1;
        h0.x = f2bf(a0.x + q0.x); h0.y = f2bf(a0.y + q0.y);
        h0.z = f2bf(a0.z + q0.z); h0.w = f2bf(a0.w + q0.w);
        h1.x = f2bf(a1.x + q1.x); h1.y = f2bf(a1.y + q1.y);
        h1.z = f2bf(a1.z + q1.z); h1.w = f2bf(a1.w + q1.w);
        *(ushort4*)(As + row * 72 + scol) = h0;
        *(ushort4*)(As + row * 72 + scol + 4) = h1;
      }
      size_t gw = (size_t)(n0 + row) * 16384 + k0 + kk + scol;
      *(uint4*)(Bs + row * 72 + scol) = *(const uint4*)(Wb + gw);
    }
    __syncthreads();
#pragma unroll
    for (int ks = 0; ks < 2; ++ks) {
      const int colb = ks * 32 + q * 8;
      s16x8 af = *(const s16x8*)(As + (16 * w + n) * 72 + colb);
#pragma unroll
      for (int c = 0; c < 4; ++c) {
        s16x8 bf = *(const s16x8*)(Bs + (16 * c + n) * 72 + colb);
        acc[c] = mfma16(af, bf, acc[c]);
      }
    }
    __syncthreads();
  }
#pragma unroll
  for (int r = 0; r < 4; ++r) {
    int m = m0 + 16 * w + 4 * q + r;
#pragma unroll
    for (int c = 0; c < 4; ++c) {
      int nn = n0 + 16 * c + n;
      part[((size_t)blockIdx.z * 2048 + m) * 256 + nn] = acc[c][r];
    }
  }
}

// ---------------- reduce K-split partials + bias + ReLU (float4) ----------------
__global__ __launch_bounds__(256) void relu_kernel(const float* __restrict__ part,
                                                   const float* __restrict__ bias,
                                                   float* __restrict__ out, int KS) {
  int i4 = blockIdx.x * 256 + threadIdx.x;  // float4 index, 131072 total
  const float4* p4 = (const float4*)part;
  float4 s = ((const float4*)bias)[i4 & 63];
  for (int ks = 0; ks < KS; ++ks) {
    float4 v = p4[(size_t)ks * 131072 + i4];
    s.x += v.x; s.y += v.y; s.z += v.z; s.w += v.w;
  }
  float4 o;
  o.x = fmaxf(s.x, 0.f); o.y = fmaxf(s.y, 0.f);
  o.z = fmaxf(s.z, 0.f); o.w = fmaxf(s.w, 0.f);
  ((float4*)out)[i4] = o;
}

extern "C" void kernel_launch(void* const* d_in, const int* in_sizes, int n_in,
                              void* d_out, int out_size, void* d_ws, size_t ws_size,
                              hipStream_t stream) {
  const float* value = (const float*)d_in[0];
  const float* key   = (const float*)d_in[1];
  const float* query = (const float*)d_in[2];
  // d_in[3] = mask, unused by the block
  const float* W_ff  = (const float*)d_in[4];
  const float* b_ff  = (const float*)d_in[5];

  float* out  = (float*)d_out;
  float* attn = out + (size_t)2048 * 256;  // outputs: (out, attention) concatenated

  const size_t wb_bytes = (size_t)256 * 16384 * 2;      // 8 MB bf16 W
  const size_t xb_bytes = (size_t)2048 * 64 * 256 * 2;  // 64 MB bf16 x
  const size_t slab     = (size_t)2048 * 256 * 4;       // 2 MB per K-split slab

  // Pick the largest K-split the workspace allows (more resident ff blocks).
  int KS;
  bool use_xb;
  if (ws_size >= wb_bytes + 16 * slab + xb_bytes) {
    KS = 16; use_xb = true;                // 2048 blocks -> 8 blocks/CU
  } else if (ws_size >= wb_bytes + 8 * slab + xb_bytes) {
    KS = 8; use_xb = true;                 // 1024 blocks -> 4 blocks/CU
  } else if (ws_size >= wb_bytes + 4 * slab + xb_bytes) {
    KS = 4; use_xb = true;                 // round-0 footprint
  } else {
    KS = 8; use_xb = false;                // ff recomputes x from attn+query
  }
  const size_t part_bytes = (size_t)KS * slab;

  unsigned short* Wb = (unsigned short*)d_ws;
  float* part = (float*)((char*)d_ws + wb_bytes);
  unsigned short* xb =
      use_xb ? (unsigned short*)((char*)d_ws + wb_bytes + part_bytes) : nullptr;

  w2b_kernel<<<4096, 256, 0, stream>>>(W_ff, Wb);
  attn_kernel<<<2048, 256, 0, stream>>>(value, key, query, attn, xb);
  dim3 gb(32, 4, KS);
  if (use_xb)
    ff_kernel<true><<<gb, 256, 0, stream>>>(xb, nullptr, nullptr, Wb, part, 16384 / KS);
  else
    ff_kernel<false><<<gb, 256, 0, stream>>>(nullptr, attn, query, Wb, part, 16384 / KS);
  relu_kernel<<<512, 256, 0, stream>>>(part, b_ff, out, KS);
}